// Round 1
// baseline (270.231 us; speedup 1.0000x reference)
//
#include <hip/hip_runtime.h>
#include <stdint.h>

// DCNv2 forward, MI355X. Pipeline:
//  K0 prep_weights : W (256,256,3,3) -> WB bf16 in MFMA-B-frag order [kk/8][o][8]
//                    p_weight (27,256,3,3) -> PWs bf16 [kk/8][j(32,pad)][8]
//  K1 transpose_x  : x NCHW -> xt NHWC fp32 (channel-contiguous for sampling)
//  K2 offset_conv  : implicit-im2col bf16 MFMA conv (N=32 pad), epilogue emits
//                    dyA/dxA/sigmoid(maskA) fp32 [m][9]
//  K3 sample       : bilinear (fp32 math) * mask -> A bf16 [m][kk], kk=k*256+c
//                    one wave = one (m,k): 4 taps x (64 lanes x float4) = 256 ch
//  K4 main_gemm    : m97-style 128x128xBK32 bf16 MFMA GEMM, global_load_lds w=16,
//                    epilogue +bias, writes NCHW fp32 out.
// Workspace requirement: ~95.4 MB.

#define NB 4
#define CIN 256
#define COUT 256
#define HH 64
#define WW 64
#define HWS 4096      // H*W
#define MTOT 16384    // B*H*W
#define KTOT 2304     // CIN*9

typedef __attribute__((ext_vector_type(8))) short bf16x8;
typedef __attribute__((ext_vector_type(4))) float f32x4;

__device__ __forceinline__ unsigned short f2bf(float f) {
  unsigned int u = __float_as_uint(f);
  unsigned int r = (u + 0x7fffu + ((u >> 16) & 1u)) >> 16;
  return (unsigned short)r;
}

__device__ __forceinline__ void gload_lds16(const void* g, void* l) {
  __builtin_amdgcn_global_load_lds((const __attribute__((address_space(1))) void*)g,
                                   (__attribute__((address_space(3))) void*)l, 16, 0, 0);
}

// ---------------- K0: weight prep ----------------
// WB flat f = ((kk>>3)*256 + o)*8 + (kk&7), kk = k*256 + c, src w[o*2304 + c*9 + k]
// PWs flat f2 = ((kk>>3)*32 + j)*8 + (kk&7), src pw[j*2304 + c*9 + k] (j<27 else 0)
__global__ __launch_bounds__(256) void prep_weights(const float* __restrict__ w,
                                                    const float* __restrict__ pw,
                                                    unsigned short* __restrict__ WB,
                                                    unsigned short* __restrict__ PWs) {
  int idx = blockIdx.x * 256 + threadIdx.x;
  if (idx < KTOT * COUT) {
    int f = idx;
    int t_ = f & 7;
    int rest = f >> 3;
    int o = rest & 255;
    int kk = (rest >> 8) * 8 + t_;
    int k = kk >> 8, c = kk & 255;
    WB[f] = f2bf(w[o * KTOT + c * 9 + k]);
  } else {
    int f2 = idx - KTOT * COUT;   // < 2304*32
    int t_ = f2 & 7;
    int rest = f2 >> 3;
    int j = rest & 31;
    int kk = (rest >> 5) * 8 + t_;
    int k = kk >> 8, c = kk & 255;
    float v = (j < 27) ? pw[j * KTOT + c * 9 + k] : 0.0f;
    PWs[f2] = f2bf(v);
  }
}

// ---------------- K1: NCHW -> NHWC transpose ----------------
__global__ __launch_bounds__(256) void transpose_x(const float* __restrict__ x,
                                                   float* __restrict__ xt) {
  __shared__ float tile[32][33];
  int b = blockIdx.z;
  int hw0 = blockIdx.x * 32;
  int c0 = blockIdx.y * 32;
  int tx = threadIdx.x, ty = threadIdx.y;
  for (int i = ty; i < 32; i += 8)
    tile[i][tx] = x[(size_t)(b * CIN + c0 + i) * HWS + hw0 + tx];
  __syncthreads();
  for (int r = ty; r < 32; r += 8)
    xt[(size_t)(b * HWS + hw0 + r) * CIN + c0 + tx] = tile[tx][r];
}

// ---------------- K2: offset conv (implicit im2col, bf16 MFMA, N=32) ----------------
__global__ __launch_bounds__(256) void offset_conv(const float* __restrict__ xt,
                                                   const unsigned short* __restrict__ PWs,
                                                   const float* __restrict__ p_bias,
                                                   float* __restrict__ dyA,
                                                   float* __restrict__ dxA,
                                                   float* __restrict__ maskA) {
  __shared__ unsigned short Al[128 * 32];
  __shared__ unsigned short Bl[1024];
  int tid = threadIdx.x;
  int lane = tid & 63, wv = tid >> 6;
  int m0 = blockIdx.x * 128;
  int b = m0 >> 12;
  int hw0 = m0 & 4095;
  f32x4 acc[2][2] = {};

  for (int t = 0; t < 72; ++t) {
    int k = t >> 3, c0 = (t & 7) * 32;
    int dyk = k / 3 - 1;
    int dxk = k % 3 - 1;
    __syncthreads();
    // stage B: 1024 ushorts
    {
      uint2 v = *(const uint2*)(PWs + (size_t)t * 1024 + tid * 4);
      *(uint2*)&Bl[tid * 4] = v;
    }
    // stage A: 128 rows x 32 fp32 -> bf16
    for (int pass = 0; pass < 4; ++pass) {
      int r = pass * 32 + (tid >> 3);
      int q = tid & 7;
      int hw = hw0 + r;
      int h = hw >> 6, ww = hw & 63;
      int y = h + dyk, xx = ww + dxk;
      float4 v = make_float4(0.f, 0.f, 0.f, 0.f);
      if ((unsigned)y < 64u && (unsigned)xx < 64u)
        v = *(const float4*)(xt + ((size_t)(((b << 12) + (y << 6) + xx)) << 8) + c0 + q * 4);
      ushort4 u;
      u.x = f2bf(v.x); u.y = f2bf(v.y); u.z = f2bf(v.z); u.w = f2bf(v.w);
      *(ushort4*)&Al[r * 32 + q * 4] = u;
    }
    __syncthreads();
    int row = lane & 15, quad = lane >> 4;
    bf16x8 af[2], bfr[2];
    for (int i = 0; i < 2; ++i)
      af[i] = *(const bf16x8*)&Al[(wv * 32 + i * 16 + row) * 32 + quad * 8];
    for (int j = 0; j < 2; ++j)
      bfr[j] = *(const bf16x8*)&Bl[(quad * 32 + j * 16 + row) * 8];
    for (int i = 0; i < 2; ++i)
      for (int j = 0; j < 2; ++j)
        acc[i][j] = __builtin_amdgcn_mfma_f32_16x16x32_bf16(af[i], bfr[j], acc[i][j], 0, 0, 0);
  }

  int row = lane & 15, quad = lane >> 4;
  for (int i = 0; i < 2; ++i)
    for (int j = 0; j < 2; ++j) {
      int n = j * 16 + row;
      if (n >= 27) continue;
      float pb = p_bias[n];
      for (int r_ = 0; r_ < 4; ++r_) {
        int m = m0 + wv * 32 + i * 16 + quad * 4 + r_;
        float val = acc[i][j][r_] + pb;
        if (n < 18) {
          if ((n & 1) == 0) dyA[m * 9 + (n >> 1)] = val;
          else              dxA[m * 9 + (n >> 1)] = val;
        } else {
          maskA[m * 9 + (n - 18)] = 1.0f / (1.0f + __expf(-val));
        }
      }
    }
}

// ---------------- K3: bilinear sampling -> A bf16 ----------------
__global__ __launch_bounds__(256) void sample_kernel(const float* __restrict__ xt,
                                                     const float* __restrict__ dyA,
                                                     const float* __restrict__ dxA,
                                                     const float* __restrict__ maskA,
                                                     unsigned short* __restrict__ A) {
  int wv = threadIdx.x >> 6;
  int lane = threadIdx.x & 63;
  int task = blockIdx.x * 4 + wv;         // < 147456
  int m = task / 9;
  int k = task - m * 9;
  int b = m >> 12, hw = m & 4095, h = hw >> 6, ww = hw & 63;

  float dy = dyA[m * 9 + k];
  float dx = dxA[m * 9 + k];
  float mk = maskA[m * 9 + k];

  float py = (float)(h - 1 + k / 3) + dy;
  float px = (float)(ww - 1 + k % 3) + dx;
  float y0f = floorf(py), x0f = floorf(px);
  float ay = py - y0f, ax = px - x0f;
  int y0 = (int)y0f, x0 = (int)x0f;

  float w00 = (1.f - ay) * (1.f - ax) * mk;
  float w01 = (1.f - ay) * ax * mk;
  float w10 = ay * (1.f - ax) * mk;
  float w11 = ay * ax * mk;

  float vy0 = ((unsigned)y0 < 64u) ? 1.f : 0.f;
  float vy1 = ((unsigned)(y0 + 1) < 64u) ? 1.f : 0.f;
  float vx0 = ((unsigned)x0 < 64u) ? 1.f : 0.f;
  float vx1 = ((unsigned)(x0 + 1) < 64u) ? 1.f : 0.f;
  w00 *= vy0 * vx0; w01 *= vy0 * vx1; w10 *= vy1 * vx0; w11 *= vy1 * vx1;

  int yc0 = min(max(y0, 0), 63), yc1 = min(max(y0 + 1, 0), 63);
  int xc0 = min(max(x0, 0), 63), xc1 = min(max(x0 + 1, 0), 63);

  const float4* base = (const float4*)(xt + ((size_t)b << 12) * CIN);
  float4 t00 = base[(yc0 * 64 + xc0) * 64 + lane];
  float4 t01 = base[(yc0 * 64 + xc1) * 64 + lane];
  float4 t10 = base[(yc1 * 64 + xc0) * 64 + lane];
  float4 t11 = base[(yc1 * 64 + xc1) * 64 + lane];

  float4 r;
  r.x = w00 * t00.x + w01 * t01.x + w10 * t10.x + w11 * t11.x;
  r.y = w00 * t00.y + w01 * t01.y + w10 * t10.y + w11 * t11.y;
  r.z = w00 * t00.z + w01 * t01.z + w10 * t10.z + w11 * t11.z;
  r.w = w00 * t00.w + w01 * t01.w + w10 * t10.w + w11 * t11.w;

  ushort4 o;
  o.x = f2bf(r.x); o.y = f2bf(r.y); o.z = f2bf(r.z); o.w = f2bf(r.w);
  *(ushort4*)(A + (size_t)m * KTOT + k * 256 + lane * 4) = o;
}

// ---------------- K4: main GEMM 128x128, BK=32, bf16 MFMA ----------------
__global__ __launch_bounds__(256) void main_gemm(const unsigned short* __restrict__ Amat,
                                                 const unsigned short* __restrict__ WB,
                                                 const float* __restrict__ bias,
                                                 float* __restrict__ out) {
  __shared__ unsigned short Al[128 * 32];
  __shared__ unsigned short Bl[4 * 128 * 8];
  int tid = threadIdx.x;
  int lane = tid & 63, wv = tid >> 6;
  int m0 = blockIdx.x * 128;
  int n0 = blockIdx.y * 128;
  int wm = (wv >> 1) * 64, wn = (wv & 1) * 64;
  f32x4 acc[4][4] = {};

  for (int t = 0; t < 72; ++t) {
    __syncthreads();
    for (int p = 0; p < 2; ++p) {
      int li = p * 256 + tid;
      const unsigned short* src = Amat + (size_t)(m0 + (li >> 2)) * KTOT + t * 32 + (li & 3) * 8;
      gload_lds16(src, &Al[li * 8]);
    }
    for (int p = 0; p < 2; ++p) {
      int li = p * 256 + tid;
      const unsigned short* src = WB + ((size_t)(4 * t + (li >> 7)) * 256 + n0 + (li & 127)) * 8;
      gload_lds16(src, &Bl[li * 8]);
    }
    __syncthreads();
    int row = lane & 15, quad = lane >> 4;
    bf16x8 af[4], bfr[4];
    for (int i = 0; i < 4; ++i)
      af[i] = *(const bf16x8*)&Al[(wm + i * 16 + row) * 32 + quad * 8];
    for (int j = 0; j < 4; ++j)
      bfr[j] = *(const bf16x8*)&Bl[(quad * 128 + wn + j * 16 + row) * 8];
    for (int i = 0; i < 4; ++i)
      for (int j = 0; j < 4; ++j)
        acc[i][j] = __builtin_amdgcn_mfma_f32_16x16x32_bf16(af[i], bfr[j], acc[i][j], 0, 0, 0);
  }

  int b = m0 >> 12, hw0 = m0 & 4095;
  int row = lane & 15, quad = lane >> 4;
  for (int j = 0; j < 4; ++j) {
    int o = n0 + wn + j * 16 + row;
    float bo = bias[o];
    for (int i = 0; i < 4; ++i) {
      int hw = hw0 + wm + i * 16 + quad * 4;
      float4 v;
      v.x = acc[i][j][0] + bo;
      v.y = acc[i][j][1] + bo;
      v.z = acc[i][j][2] + bo;
      v.w = acc[i][j][3] + bo;
      *(float4*)(out + (((size_t)(b * COUT + o)) << 12) + hw) = v;
    }
  }
}

// ---------------- launch ----------------
extern "C" void kernel_launch(void* const* d_in, const int* in_sizes, int n_in,
                              void* d_out, int out_size, void* d_ws, size_t ws_size,
                              hipStream_t stream) {
  const float* x        = (const float*)d_in[0];
  const float* weight   = (const float*)d_in[1];
  const float* bias     = (const float*)d_in[2];
  const float* p_weight = (const float*)d_in[3];
  const float* p_bias   = (const float*)d_in[4];
  float* out = (float*)d_out;
  char* ws = (char*)d_ws;

  // workspace layout (bytes); total 95,371,264
  const size_t OFF_XT   = 0;                          // 16,777,216  fp32 NHWC x
  const size_t OFF_DY   = 16777216;                   //    589,824
  const size_t OFF_DX   = OFF_DY + 589824;            //    589,824
  const size_t OFF_MASK = OFF_DX + 589824;            //    589,824
  const size_t OFF_WB   = OFF_MASK + 589824;          //  1,179,648  bf16
  const size_t OFF_PW   = OFF_WB + 1179648;           //    147,456  bf16
  const size_t OFF_A    = OFF_PW + 147456;            // 75,497,472  bf16

  float* xt   = (float*)(ws + OFF_XT);
  float* dyA  = (float*)(ws + OFF_DY);
  float* dxA  = (float*)(ws + OFF_DX);
  float* mskA = (float*)(ws + OFF_MASK);
  unsigned short* WB   = (unsigned short*)(ws + OFF_WB);
  unsigned short* PWs  = (unsigned short*)(ws + OFF_PW);
  unsigned short* Amat = (unsigned short*)(ws + OFF_A);

  prep_weights<<<(KTOT * COUT + KTOT * 32) / 256, 256, 0, stream>>>(weight, p_weight, WB, PWs);
  transpose_x<<<dim3(128, 8, 4), dim3(32, 8), 0, stream>>>(x, xt);
  offset_conv<<<MTOT / 128, 256, 0, stream>>>(xt, PWs, p_bias, dyA, dxA, mskA);
  sample_kernel<<<(MTOT * 9) / 4, 256, 0, stream>>>(xt, dyA, dxA, mskA, Amat);
  main_gemm<<<dim3(MTOT / 128, COUT / 128), 256, 0, stream>>>(Amat, WB, bias, out);
}

// Round 2
// 192.503 us; speedup vs baseline: 1.4038x; 1.4038x over previous
//
#include <hip/hip_runtime.h>
#include <stdint.h>

// DCNv2 forward, MI355X. Pipeline:
//  K0 prep_weights : W -> WB bf16 MFMA-B order; p_weight -> PWs bf16 (N=32 pad)
//  K1 transpose_x  : x NCHW -> xt NHWC fp32
//  K2 offset_conv_sk : split-K (S=8) implicit-im2col bf16 MFMA conv, BM=64,
//                      2048 blocks (8/CU) -> fp32 partials Pbuf[s][m][32]
//  K2b reduce_offsets: sum 8 partials + bias -> dy/dx/sigmoid(mask)
//  K3 sample       : bilinear (fp32) * mask -> A bf16 [m][kk], kk=k*256+c
//  K4 main_gemm    : 128x128xBK32 bf16 MFMA GEMM, global_load_lds w=16,
//                    epilogue +bias, writes NCHW fp32 out.
// Workspace: 95.4 MB (Pbuf 16.8 MB aliases the head of the Amat region —
// consumed by reduce_offsets before sample_kernel overwrites it).

#define NB 4
#define CIN 256
#define COUT 256
#define HWS 4096      // H*W
#define MTOT 16384    // B*H*W
#define KTOT 2304     // CIN*9
#define SPLITK 8

typedef __attribute__((ext_vector_type(8))) short bf16x8;
typedef __attribute__((ext_vector_type(4))) float f32x4;

__device__ __forceinline__ unsigned short f2bf(float f) {
  unsigned int u = __float_as_uint(f);
  unsigned int r = (u + 0x7fffu + ((u >> 16) & 1u)) >> 16;
  return (unsigned short)r;
}

__device__ __forceinline__ void gload_lds16(const void* g, void* l) {
  __builtin_amdgcn_global_load_lds((const __attribute__((address_space(1))) void*)g,
                                   (__attribute__((address_space(3))) void*)l, 16, 0, 0);
}

// ---------------- K0: weight prep ----------------
__global__ __launch_bounds__(256) void prep_weights(const float* __restrict__ w,
                                                    const float* __restrict__ pw,
                                                    unsigned short* __restrict__ WB,
                                                    unsigned short* __restrict__ PWs) {
  int idx = blockIdx.x * 256 + threadIdx.x;
  if (idx < KTOT * COUT) {
    int f = idx;
    int t_ = f & 7;
    int rest = f >> 3;
    int o = rest & 255;
    int kk = (rest >> 8) * 8 + t_;
    int k = kk >> 8, c = kk & 255;
    WB[f] = f2bf(w[o * KTOT + c * 9 + k]);
  } else {
    int f2 = idx - KTOT * COUT;   // < 2304*32
    int t_ = f2 & 7;
    int rest = f2 >> 3;
    int j = rest & 31;
    int kk = (rest >> 5) * 8 + t_;
    int k = kk >> 8, c = kk & 255;
    float v = (j < 27) ? pw[j * KTOT + c * 9 + k] : 0.0f;
    PWs[f2] = f2bf(v);
  }
}

// ---------------- K1: NCHW -> NHWC transpose ----------------
__global__ __launch_bounds__(256) void transpose_x(const float* __restrict__ x,
                                                   float* __restrict__ xt) {
  __shared__ float tile[32][33];
  int b = blockIdx.z;
  int hw0 = blockIdx.x * 32;
  int c0 = blockIdx.y * 32;
  int tx = threadIdx.x, ty = threadIdx.y;
  for (int i = ty; i < 32; i += 8)
    tile[i][tx] = x[(size_t)(b * CIN + c0 + i) * HWS + hw0 + tx];
  __syncthreads();
  for (int r = ty; r < 32; r += 8)
    xt[(size_t)(b * HWS + hw0 + r) * CIN + c0 + tx] = tile[tx][r];
}

// ---------------- K2: offset conv, split-K, BM=64 ----------------
// grid (MTOT/64, SPLITK). Each block: 9 K-iters of BK=32, writes fp32
// partials Pbuf[s*MTOT*32 + m*32 + n] (no atomics).
__global__ __launch_bounds__(256) void offset_conv_sk(const float* __restrict__ xt,
                                                      const unsigned short* __restrict__ PWs,
                                                      float* __restrict__ Pbuf) {
  __shared__ unsigned short Al[64 * 32];   // 4 KB
  __shared__ unsigned short Bl[1024];      // 2 KB
  int tid = threadIdx.x;
  int lane = tid & 63, wv = tid >> 6;
  int m0 = blockIdx.x * 64;
  int s = blockIdx.y;
  int b = m0 >> 12;
  int hw0 = m0 & 4095;
  f32x4 acc[2] = {};

  for (int tt = 0; tt < 72 / SPLITK; ++tt) {
    int t = s * (72 / SPLITK) + tt;
    int k = t >> 3, c0 = (t & 7) * 32;
    int dyk = k / 3 - 1;
    int dxk = k % 3 - 1;
    __syncthreads();
    // stage B: 1024 ushorts (32 kk x 32 j)
    *(uint2*)&Bl[tid * 4] = *(const uint2*)(PWs + (size_t)t * 1024 + tid * 4);
    // stage A: 64 rows x 32 fp32 -> bf16; thread covers 8 channels of one row
    {
      int r = tid >> 2;
      int q = (tid & 3) * 8;
      int hw = hw0 + r;
      int h = hw >> 6, wwp = hw & 63;
      int y = h + dyk, xx = wwp + dxk;
      float4 v0 = make_float4(0.f, 0.f, 0.f, 0.f);
      float4 v1 = make_float4(0.f, 0.f, 0.f, 0.f);
      if ((unsigned)y < 64u && (unsigned)xx < 64u) {
        const float* p = xt + ((size_t)((b << 12) + (y << 6) + xx) << 8) + c0 + q;
        v0 = *(const float4*)p;
        v1 = *(const float4*)(p + 4);
      }
      unsigned short u[8];
      u[0] = f2bf(v0.x); u[1] = f2bf(v0.y); u[2] = f2bf(v0.z); u[3] = f2bf(v0.w);
      u[4] = f2bf(v1.x); u[5] = f2bf(v1.y); u[6] = f2bf(v1.z); u[7] = f2bf(v1.w);
      *(uint4*)&Al[r * 32 + q] = *(const uint4*)u;
    }
    __syncthreads();
    int row = lane & 15, quad = lane >> 4;
    bf16x8 af = *(const bf16x8*)&Al[(wv * 16 + row) * 32 + quad * 8];
    for (int j = 0; j < 2; ++j) {
      bf16x8 bfr = *(const bf16x8*)&Bl[(quad * 32 + j * 16 + row) * 8];
      acc[j] = __builtin_amdgcn_mfma_f32_16x16x32_bf16(af, bfr, acc[j], 0, 0, 0);
    }
  }

  int row = lane & 15, quad = lane >> 4;
  for (int j = 0; j < 2; ++j) {
    int n = j * 16 + row;
    for (int r_ = 0; r_ < 4; ++r_) {
      int m = m0 + wv * 16 + quad * 4 + r_;
      Pbuf[((size_t)s * MTOT + m) * 32 + n] = acc[j][r_];
    }
  }
}

// ---------------- K2b: reduce split-K partials -> dy/dx/mask ----------------
__global__ __launch_bounds__(256) void reduce_offsets(const float* __restrict__ Pbuf,
                                                      const float* __restrict__ p_bias,
                                                      float* __restrict__ dyA,
                                                      float* __restrict__ dxA,
                                                      float* __restrict__ maskA) {
  int idx = blockIdx.x * 256 + threadIdx.x;  // m*32+n
  int n = idx & 31;
  int m = idx >> 5;
  float v = 0.f;
#pragma unroll
  for (int s = 0; s < SPLITK; ++s)
    v += Pbuf[(size_t)s * MTOT * 32 + idx];
  if (n < 27) {
    v += p_bias[n];
    if (n < 18) {
      if ((n & 1) == 0) dyA[m * 9 + (n >> 1)] = v;
      else              dxA[m * 9 + (n >> 1)] = v;
    } else {
      maskA[m * 9 + (n - 18)] = 1.0f / (1.0f + __expf(-v));
    }
  }
}

// ---------------- K3: bilinear sampling -> A bf16 ----------------
__global__ __launch_bounds__(256) void sample_kernel(const float* __restrict__ xt,
                                                     const float* __restrict__ dyA,
                                                     const float* __restrict__ dxA,
                                                     const float* __restrict__ maskA,
                                                     unsigned short* __restrict__ A) {
  int wv = threadIdx.x >> 6;
  int lane = threadIdx.x & 63;
  int task = blockIdx.x * 4 + wv;         // < 147456
  int m = task / 9;
  int k = task - m * 9;
  int b = m >> 12, hw = m & 4095, h = hw >> 6, ww = hw & 63;

  float dy = dyA[m * 9 + k];
  float dx = dxA[m * 9 + k];
  float mk = maskA[m * 9 + k];

  float py = (float)(h - 1 + k / 3) + dy;
  float px = (float)(ww - 1 + k % 3) + dx;
  float y0f = floorf(py), x0f = floorf(px);
  float ay = py - y0f, ax = px - x0f;
  int y0 = (int)y0f, x0 = (int)x0f;

  float w00 = (1.f - ay) * (1.f - ax) * mk;
  float w01 = (1.f - ay) * ax * mk;
  float w10 = ay * (1.f - ax) * mk;
  float w11 = ay * ax * mk;

  float vy0 = ((unsigned)y0 < 64u) ? 1.f : 0.f;
  float vy1 = ((unsigned)(y0 + 1) < 64u) ? 1.f : 0.f;
  float vx0 = ((unsigned)x0 < 64u) ? 1.f : 0.f;
  float vx1 = ((unsigned)(x0 + 1) < 64u) ? 1.f : 0.f;
  w00 *= vy0 * vx0; w01 *= vy0 * vx1; w10 *= vy1 * vx0; w11 *= vy1 * vx1;

  int yc0 = min(max(y0, 0), 63), yc1 = min(max(y0 + 1, 0), 63);
  int xc0 = min(max(x0, 0), 63), xc1 = min(max(x0 + 1, 0), 63);

  const float4* base = (const float4*)(xt + ((size_t)b << 12) * CIN);
  float4 t00 = base[(yc0 * 64 + xc0) * 64 + lane];
  float4 t01 = base[(yc0 * 64 + xc1) * 64 + lane];
  float4 t10 = base[(yc1 * 64 + xc0) * 64 + lane];
  float4 t11 = base[(yc1 * 64 + xc1) * 64 + lane];

  float4 r;
  r.x = w00 * t00.x + w01 * t01.x + w10 * t10.x + w11 * t11.x;
  r.y = w00 * t00.y + w01 * t01.y + w10 * t10.y + w11 * t11.y;
  r.z = w00 * t00.z + w01 * t01.z + w10 * t10.z + w11 * t11.z;
  r.w = w00 * t00.w + w01 * t01.w + w10 * t10.w + w11 * t11.w;

  ushort4 o;
  o.x = f2bf(r.x); o.y = f2bf(r.y); o.z = f2bf(r.z); o.w = f2bf(r.w);
  *(ushort4*)(A + (size_t)m * KTOT + k * 256 + lane * 4) = o;
}

// ---------------- K4: main GEMM 128x128, BK=32, bf16 MFMA ----------------
__global__ __launch_bounds__(256) void main_gemm(const unsigned short* __restrict__ Amat,
                                                 const unsigned short* __restrict__ WB,
                                                 const float* __restrict__ bias,
                                                 float* __restrict__ out) {
  __shared__ unsigned short Al[128 * 32];
  __shared__ unsigned short Bl[4 * 128 * 8];
  int tid = threadIdx.x;
  int lane = tid & 63, wv = tid >> 6;
  int m0 = blockIdx.x * 128;
  int n0 = blockIdx.y * 128;
  int wm = (wv >> 1) * 64, wn = (wv & 1) * 64;
  f32x4 acc[4][4] = {};

  for (int t = 0; t < 72; ++t) {
    __syncthreads();
    for (int p = 0; p < 2; ++p) {
      int li = p * 256 + tid;
      const unsigned short* src = Amat + (size_t)(m0 + (li >> 2)) * KTOT + t * 32 + (li & 3) * 8;
      gload_lds16(src, &Al[li * 8]);
    }
    for (int p = 0; p < 2; ++p) {
      int li = p * 256 + tid;
      const unsigned short* src = WB + ((size_t)(4 * t + (li >> 7)) * 256 + n0 + (li & 127)) * 8;
      gload_lds16(src, &Bl[li * 8]);
    }
    __syncthreads();
    int row = lane & 15, quad = lane >> 4;
    bf16x8 af[4], bfr[4];
    for (int i = 0; i < 4; ++i)
      af[i] = *(const bf16x8*)&Al[(wm + i * 16 + row) * 32 + quad * 8];
    for (int j = 0; j < 4; ++j)
      bfr[j] = *(const bf16x8*)&Bl[(quad * 128 + wn + j * 16 + row) * 8];
    for (int i = 0; i < 4; ++i)
      for (int j = 0; j < 4; ++j)
        acc[i][j] = __builtin_amdgcn_mfma_f32_16x16x32_bf16(af[i], bfr[j], acc[i][j], 0, 0, 0);
  }

  int b = m0 >> 12, hw0 = m0 & 4095;
  int row = lane & 15, quad = lane >> 4;
  for (int j = 0; j < 4; ++j) {
    int o = n0 + wn + j * 16 + row;
    float bo = bias[o];
    for (int i = 0; i < 4; ++i) {
      int hw = hw0 + wm + i * 16 + quad * 4;
      float4 v;
      v.x = acc[i][j][0] + bo;
      v.y = acc[i][j][1] + bo;
      v.z = acc[i][j][2] + bo;
      v.w = acc[i][j][3] + bo;
      *(float4*)(out + (((size_t)(b * COUT + o)) << 12) + hw) = v;
    }
  }
}

// ---------------- launch ----------------
extern "C" void kernel_launch(void* const* d_in, const int* in_sizes, int n_in,
                              void* d_out, int out_size, void* d_ws, size_t ws_size,
                              hipStream_t stream) {
  const float* x        = (const float*)d_in[0];
  const float* weight   = (const float*)d_in[1];
  const float* bias     = (const float*)d_in[2];
  const float* p_weight = (const float*)d_in[3];
  const float* p_bias   = (const float*)d_in[4];
  float* out = (float*)d_out;
  char* ws = (char*)d_ws;

  // workspace layout (bytes); total 95,371,264
  const size_t OFF_XT   = 0;                          // 16,777,216  fp32 NHWC x
  const size_t OFF_DY   = 16777216;                   //    589,824
  const size_t OFF_DX   = OFF_DY + 589824;            //    589,824
  const size_t OFF_MASK = OFF_DX + 589824;            //    589,824
  const size_t OFF_WB   = OFF_MASK + 589824;          //  1,179,648  bf16
  const size_t OFF_PW   = OFF_WB + 1179648;           //    147,456  bf16
  const size_t OFF_A    = OFF_PW + 147456;            // 75,497,472  bf16
  // Pbuf (16.8 MB fp32) aliases head of Amat region: consumed by
  // reduce_offsets before sample_kernel writes Amat.

  float* xt   = (float*)(ws + OFF_XT);
  float* dyA  = (float*)(ws + OFF_DY);
  float* dxA  = (float*)(ws + OFF_DX);
  float* mskA = (float*)(ws + OFF_MASK);
  unsigned short* WB   = (unsigned short*)(ws + OFF_WB);
  unsigned short* PWs  = (unsigned short*)(ws + OFF_PW);
  unsigned short* Amat = (unsigned short*)(ws + OFF_A);
  float* Pbuf = (float*)(ws + OFF_A);

  prep_weights<<<(KTOT * COUT + KTOT * 32) / 256, 256, 0, stream>>>(weight, p_weight, WB, PWs);
  transpose_x<<<dim3(128, 8, 4), dim3(32, 8), 0, stream>>>(x, xt);
  offset_conv_sk<<<dim3(MTOT / 64, SPLITK), 256, 0, stream>>>(xt, PWs, Pbuf);
  reduce_offsets<<<(MTOT * 32) / 256, 256, 0, stream>>>(Pbuf, p_bias, dyA, dxA, mskA);
  sample_kernel<<<(MTOT * 9) / 4, 256, 0, stream>>>(xt, dyA, dxA, mskA, Amat);
  main_gemm<<<dim3(MTOT / 128, COUT / 128), 256, 0, stream>>>(Amat, WB, bias, out);
}

// Round 3
// 181.908 us; speedup vs baseline: 1.4855x; 1.0582x over previous
//
#include <hip/hip_runtime.h>
#include <stdint.h>

// DCNv2 forward, MI355X. Pipeline:
//  K0 prep_weights : W -> WB bf16 MFMA-B order; p_weight -> PWs bf16 (N=32 pad)
//  K1 transpose_x  : x NCHW -> xt NHWC fp32
//  K2 offset_conv_sk : split-K (S=8) implicit-im2col bf16 MFMA conv, BM=64,
//                      2048 blocks (8/CU) -> fp32 partials Pbuf[s][m][32]
//  K2b reduce_offsets: sum 8 partials + bias -> dy/dx/sigmoid(mask)
//  K3 sample       : bilinear (fp32) * mask -> A bf16 [m][kk], kk=k*256+c
//  K4 main_gemm    : 128x64xBK32 bf16 MFMA GEMM (512 blocks = 2/CU),
//                    global_load_lds w=16, epilogue +bias, NCHW fp32 out.
// Workspace: 95.4 MB (Pbuf 16.8 MB aliases the head of the Amat region —
// consumed by reduce_offsets before sample_kernel overwrites it).

#define NB 4
#define CIN 256
#define COUT 256
#define HWS 4096      // H*W
#define MTOT 16384    // B*H*W
#define KTOT 2304     // CIN*9
#define SPLITK 8

typedef __attribute__((ext_vector_type(8))) short bf16x8;
typedef __attribute__((ext_vector_type(4))) float f32x4;

__device__ __forceinline__ unsigned short f2bf(float f) {
  unsigned int u = __float_as_uint(f);
  unsigned int r = (u + 0x7fffu + ((u >> 16) & 1u)) >> 16;
  return (unsigned short)r;
}

__device__ __forceinline__ void gload_lds16(const void* g, void* l) {
  __builtin_amdgcn_global_load_lds((const __attribute__((address_space(1))) void*)g,
                                   (__attribute__((address_space(3))) void*)l, 16, 0, 0);
}

// ---------------- K0: weight prep ----------------
__global__ __launch_bounds__(256) void prep_weights(const float* __restrict__ w,
                                                    const float* __restrict__ pw,
                                                    unsigned short* __restrict__ WB,
                                                    unsigned short* __restrict__ PWs) {
  int idx = blockIdx.x * 256 + threadIdx.x;
  if (idx < KTOT * COUT) {
    int f = idx;
    int t_ = f & 7;
    int rest = f >> 3;
    int o = rest & 255;
    int kk = (rest >> 8) * 8 + t_;
    int k = kk >> 8, c = kk & 255;
    WB[f] = f2bf(w[o * KTOT + c * 9 + k]);
  } else {
    int f2 = idx - KTOT * COUT;   // < 2304*32
    int t_ = f2 & 7;
    int rest = f2 >> 3;
    int j = rest & 31;
    int kk = (rest >> 5) * 8 + t_;
    int k = kk >> 8, c = kk & 255;
    float v = (j < 27) ? pw[j * KTOT + c * 9 + k] : 0.0f;
    PWs[f2] = f2bf(v);
  }
}

// ---------------- K1: NCHW -> NHWC transpose ----------------
__global__ __launch_bounds__(256) void transpose_x(const float* __restrict__ x,
                                                   float* __restrict__ xt) {
  __shared__ float tile[32][33];
  int b = blockIdx.z;
  int hw0 = blockIdx.x * 32;
  int c0 = blockIdx.y * 32;
  int tx = threadIdx.x, ty = threadIdx.y;
  for (int i = ty; i < 32; i += 8)
    tile[i][tx] = x[(size_t)(b * CIN + c0 + i) * HWS + hw0 + tx];
  __syncthreads();
  for (int r = ty; r < 32; r += 8)
    xt[(size_t)(b * HWS + hw0 + r) * CIN + c0 + tx] = tile[tx][r];
}

// ---------------- K2: offset conv, split-K, BM=64 ----------------
__global__ __launch_bounds__(256) void offset_conv_sk(const float* __restrict__ xt,
                                                      const unsigned short* __restrict__ PWs,
                                                      float* __restrict__ Pbuf) {
  __shared__ unsigned short Al[64 * 32];   // 4 KB
  __shared__ unsigned short Bl[1024];      // 2 KB
  int tid = threadIdx.x;
  int lane = tid & 63, wv = tid >> 6;
  int m0 = blockIdx.x * 64;
  int s = blockIdx.y;
  int b = m0 >> 12;
  int hw0 = m0 & 4095;
  f32x4 acc[2] = {};

  for (int tt = 0; tt < 72 / SPLITK; ++tt) {
    int t = s * (72 / SPLITK) + tt;
    int k = t >> 3, c0 = (t & 7) * 32;
    int dyk = k / 3 - 1;
    int dxk = k % 3 - 1;
    __syncthreads();
    *(uint2*)&Bl[tid * 4] = *(const uint2*)(PWs + (size_t)t * 1024 + tid * 4);
    {
      int r = tid >> 2;
      int q = (tid & 3) * 8;
      int hw = hw0 + r;
      int h = hw >> 6, wwp = hw & 63;
      int y = h + dyk, xx = wwp + dxk;
      float4 v0 = make_float4(0.f, 0.f, 0.f, 0.f);
      float4 v1 = make_float4(0.f, 0.f, 0.f, 0.f);
      if ((unsigned)y < 64u && (unsigned)xx < 64u) {
        const float* p = xt + ((size_t)((b << 12) + (y << 6) + xx) << 8) + c0 + q;
        v0 = *(const float4*)p;
        v1 = *(const float4*)(p + 4);
      }
      unsigned short u[8];
      u[0] = f2bf(v0.x); u[1] = f2bf(v0.y); u[2] = f2bf(v0.z); u[3] = f2bf(v0.w);
      u[4] = f2bf(v1.x); u[5] = f2bf(v1.y); u[6] = f2bf(v1.z); u[7] = f2bf(v1.w);
      *(uint4*)&Al[r * 32 + q] = *(const uint4*)u;
    }
    __syncthreads();
    int row = lane & 15, quad = lane >> 4;
    bf16x8 af = *(const bf16x8*)&Al[(wv * 16 + row) * 32 + quad * 8];
    for (int j = 0; j < 2; ++j) {
      bf16x8 bfr = *(const bf16x8*)&Bl[(quad * 32 + j * 16 + row) * 8];
      acc[j] = __builtin_amdgcn_mfma_f32_16x16x32_bf16(af, bfr, acc[j], 0, 0, 0);
    }
  }

  int row = lane & 15, quad = lane >> 4;
  for (int j = 0; j < 2; ++j) {
    int n = j * 16 + row;
    for (int r_ = 0; r_ < 4; ++r_) {
      int m = m0 + wv * 16 + quad * 4 + r_;
      Pbuf[((size_t)s * MTOT + m) * 32 + n] = acc[j][r_];
    }
  }
}

// ---------------- K2b: reduce split-K partials -> dy/dx/mask ----------------
__global__ __launch_bounds__(256) void reduce_offsets(const float* __restrict__ Pbuf,
                                                      const float* __restrict__ p_bias,
                                                      float* __restrict__ dyA,
                                                      float* __restrict__ dxA,
                                                      float* __restrict__ maskA) {
  int idx = blockIdx.x * 256 + threadIdx.x;  // m*32+n
  int n = idx & 31;
  int m = idx >> 5;
  float v = 0.f;
#pragma unroll
  for (int s = 0; s < SPLITK; ++s)
    v += Pbuf[(size_t)s * MTOT * 32 + idx];
  if (n < 27) {
    v += p_bias[n];
    if (n < 18) {
      if ((n & 1) == 0) dyA[m * 9 + (n >> 1)] = v;
      else              dxA[m * 9 + (n >> 1)] = v;
    } else {
      maskA[m * 9 + (n - 18)] = 1.0f / (1.0f + __expf(-v));
    }
  }
}

// ---------------- K3: bilinear sampling -> A bf16 ----------------
__global__ __launch_bounds__(256) void sample_kernel(const float* __restrict__ xt,
                                                     const float* __restrict__ dyA,
                                                     const float* __restrict__ dxA,
                                                     const float* __restrict__ maskA,
                                                     unsigned short* __restrict__ A) {
  int wv = threadIdx.x >> 6;
  int lane = threadIdx.x & 63;
  int task = blockIdx.x * 4 + wv;         // < 147456
  int m = task / 9;
  int k = task - m * 9;
  int b = m >> 12, hw = m & 4095, h = hw >> 6, ww = hw & 63;

  float dy = dyA[m * 9 + k];
  float dx = dxA[m * 9 + k];
  float mk = maskA[m * 9 + k];

  float py = (float)(h - 1 + k / 3) + dy;
  float px = (float)(ww - 1 + k % 3) + dx;
  float y0f = floorf(py), x0f = floorf(px);
  float ay = py - y0f, ax = px - x0f;
  int y0 = (int)y0f, x0 = (int)x0f;

  float w00 = (1.f - ay) * (1.f - ax) * mk;
  float w01 = (1.f - ay) * ax * mk;
  float w10 = ay * (1.f - ax) * mk;
  float w11 = ay * ax * mk;

  float vy0 = ((unsigned)y0 < 64u) ? 1.f : 0.f;
  float vy1 = ((unsigned)(y0 + 1) < 64u) ? 1.f : 0.f;
  float vx0 = ((unsigned)x0 < 64u) ? 1.f : 0.f;
  float vx1 = ((unsigned)(x0 + 1) < 64u) ? 1.f : 0.f;
  w00 *= vy0 * vx0; w01 *= vy0 * vx1; w10 *= vy1 * vx0; w11 *= vy1 * vx1;

  int yc0 = min(max(y0, 0), 63), yc1 = min(max(y0 + 1, 0), 63);
  int xc0 = min(max(x0, 0), 63), xc1 = min(max(x0 + 1, 0), 63);

  const float4* base = (const float4*)(xt + ((size_t)b << 12) * CIN);
  float4 t00 = base[(yc0 * 64 + xc0) * 64 + lane];
  float4 t01 = base[(yc0 * 64 + xc1) * 64 + lane];
  float4 t10 = base[(yc1 * 64 + xc0) * 64 + lane];
  float4 t11 = base[(yc1 * 64 + xc1) * 64 + lane];

  float4 r;
  r.x = w00 * t00.x + w01 * t01.x + w10 * t10.x + w11 * t11.x;
  r.y = w00 * t00.y + w01 * t01.y + w10 * t10.y + w11 * t11.y;
  r.z = w00 * t00.z + w01 * t01.z + w10 * t10.z + w11 * t11.z;
  r.w = w00 * t00.w + w01 * t01.w + w10 * t10.w + w11 * t11.w;

  ushort4 o;
  o.x = f2bf(r.x); o.y = f2bf(r.y); o.z = f2bf(r.z); o.w = f2bf(r.w);
  *(ushort4*)(A + (size_t)m * KTOT + k * 256 + lane * 4) = o;
}

// ---------------- K4: main GEMM 128x64, BK=32, bf16 MFMA (2 blocks/CU) ----------------
__global__ __launch_bounds__(256) void main_gemm(const unsigned short* __restrict__ Amat,
                                                 const unsigned short* __restrict__ WB,
                                                 const float* __restrict__ bias,
                                                 float* __restrict__ out) {
  __shared__ unsigned short Al[128 * 32];   // 8 KB
  __shared__ unsigned short Bl[4 * 64 * 8]; // 4 KB
  int tid = threadIdx.x;
  int lane = tid & 63, wv = tid >> 6;
  int m0 = blockIdx.x * 128;
  int n0 = blockIdx.y * 64;
  int wm = wv * 32;                          // wave covers rows [wm, wm+32), all 64 cols
  f32x4 acc[2][4] = {};

  for (int t = 0; t < 72; ++t) {
    __syncthreads();
    for (int p = 0; p < 2; ++p) {
      int li = p * 256 + tid;
      const unsigned short* src = Amat + (size_t)(m0 + (li >> 2)) * KTOT + t * 32 + (li & 3) * 8;
      gload_lds16(src, &Al[li * 8]);
    }
    {
      int li = tid;   // 256 chunks of 16B = 4 KB
      const unsigned short* src = WB + ((size_t)(4 * t + (li >> 6)) * 256 + n0 + (li & 63)) * 8;
      gload_lds16(src, &Bl[li * 8]);
    }
    __syncthreads();
    int row = lane & 15, quad = lane >> 4;
    bf16x8 af[2], bfr[4];
    for (int i = 0; i < 2; ++i)
      af[i] = *(const bf16x8*)&Al[(wm + i * 16 + row) * 32 + quad * 8];
    for (int j = 0; j < 4; ++j)
      bfr[j] = *(const bf16x8*)&Bl[(quad * 64 + j * 16 + row) * 8];
    for (int i = 0; i < 2; ++i)
      for (int j = 0; j < 4; ++j)
        acc[i][j] = __builtin_amdgcn_mfma_f32_16x16x32_bf16(af[i], bfr[j], acc[i][j], 0, 0, 0);
  }

  int b = m0 >> 12, hw0 = m0 & 4095;
  int row = lane & 15, quad = lane >> 4;
  for (int j = 0; j < 4; ++j) {
    int o = n0 + j * 16 + row;
    float bo = bias[o];
    for (int i = 0; i < 2; ++i) {
      int hw = hw0 + wm + i * 16 + quad * 4;
      float4 v;
      v.x = acc[i][j][0] + bo;
      v.y = acc[i][j][1] + bo;
      v.z = acc[i][j][2] + bo;
      v.w = acc[i][j][3] + bo;
      *(float4*)(out + (((size_t)(b * COUT + o)) << 12) + hw) = v;
    }
  }
}

// ---------------- launch ----------------
extern "C" void kernel_launch(void* const* d_in, const int* in_sizes, int n_in,
                              void* d_out, int out_size, void* d_ws, size_t ws_size,
                              hipStream_t stream) {
  const float* x        = (const float*)d_in[0];
  const float* weight   = (const float*)d_in[1];
  const float* bias     = (const float*)d_in[2];
  const float* p_weight = (const float*)d_in[3];
  const float* p_bias   = (const float*)d_in[4];
  float* out = (float*)d_out;
  char* ws = (char*)d_ws;

  const size_t OFF_XT   = 0;                          // 16,777,216  fp32 NHWC x
  const size_t OFF_DY   = 16777216;                   //    589,824
  const size_t OFF_DX   = OFF_DY + 589824;            //    589,824
  const size_t OFF_MASK = OFF_DX + 589824;            //    589,824
  const size_t OFF_WB   = OFF_MASK + 589824;          //  1,179,648  bf16
  const size_t OFF_PW   = OFF_WB + 1179648;           //    147,456  bf16
  const size_t OFF_A    = OFF_PW + 147456;            // 75,497,472  bf16

  float* xt   = (float*)(ws + OFF_XT);
  float* dyA  = (float*)(ws + OFF_DY);
  float* dxA  = (float*)(ws + OFF_DX);
  float* mskA = (float*)(ws + OFF_MASK);
  unsigned short* WB   = (unsigned short*)(ws + OFF_WB);
  unsigned short* PWs  = (unsigned short*)(ws + OFF_PW);
  unsigned short* Amat = (unsigned short*)(ws + OFF_A);
  float* Pbuf = (float*)(ws + OFF_A);

  prep_weights<<<(KTOT * COUT + KTOT * 32) / 256, 256, 0, stream>>>(weight, p_weight, WB, PWs);
  transpose_x<<<dim3(128, 8, 4), dim3(32, 8), 0, stream>>>(x, xt);
  offset_conv_sk<<<dim3(MTOT / 64, SPLITK), 256, 0, stream>>>(xt, PWs, Pbuf);
  reduce_offsets<<<(MTOT * 32) / 256, 256, 0, stream>>>(Pbuf, p_bias, dyA, dxA, mskA);
  sample_kernel<<<(MTOT * 9) / 4, 256, 0, stream>>>(xt, dyA, dxA, mskA, Amat);
  main_gemm<<<dim3(MTOT / 128, COUT / 64), 256, 0, stream>>>(Amat, WB, bias, out);
}

// Round 4
// 171.580 us; speedup vs baseline: 1.5750x; 1.0602x over previous
//
#include <hip/hip_runtime.h>
#include <stdint.h>

// DCNv2 forward, MI355X. Pipeline:
//  K0 prep_weights : W -> WB bf16 MFMA-B order; p_weight -> PWs bf16 (N=32 pad)
//  K1 transpose_x  : x NCHW -> xt NHWC fp32
//  K2 offset_conv_sk : split-K (S=8) implicit-im2col bf16 MFMA conv, BM=64,
//                      2048 blocks (8/CU) -> fp32 partials Pbuf[s][m][32]
//  K2b reduce_offsets: sum 8 partials + bias -> dy/dx/sigmoid(mask)
//  K3 sample       : bilinear (fp32) * mask -> A bf16 [m][kk], kk=k*256+c
//  K4 main_gemm    : 128x64 tile, BK=64 (2x32 bank-safe sub-tiles), ping-pong
//                    LDS double-buffer, ONE barrier/iter, 36 iters, prefetch
//                    overlaps compute so the vmcnt(0) barrier drain is covered.
// Workspace: 95.4 MB (Pbuf 16.8 MB aliases the head of the Amat region).

#define NB 4
#define CIN 256
#define COUT 256
#define HWS 4096      // H*W
#define MTOT 16384    // B*H*W
#define KTOT 2304     // CIN*9
#define SPLITK 8

typedef __attribute__((ext_vector_type(8))) short bf16x8;
typedef __attribute__((ext_vector_type(4))) float f32x4;

__device__ __forceinline__ unsigned short f2bf(float f) {
  unsigned int u = __float_as_uint(f);
  unsigned int r = (u + 0x7fffu + ((u >> 16) & 1u)) >> 16;
  return (unsigned short)r;
}

__device__ __forceinline__ void gload_lds16(const void* g, void* l) {
  __builtin_amdgcn_global_load_lds((const __attribute__((address_space(1))) void*)g,
                                   (__attribute__((address_space(3))) void*)l, 16, 0, 0);
}

// ---------------- K0: weight prep ----------------
__global__ __launch_bounds__(256) void prep_weights(const float* __restrict__ w,
                                                    const float* __restrict__ pw,
                                                    unsigned short* __restrict__ WB,
                                                    unsigned short* __restrict__ PWs) {
  int idx = blockIdx.x * 256 + threadIdx.x;
  if (idx < KTOT * COUT) {
    int f = idx;
    int t_ = f & 7;
    int rest = f >> 3;
    int o = rest & 255;
    int kk = (rest >> 8) * 8 + t_;
    int k = kk >> 8, c = kk & 255;
    WB[f] = f2bf(w[o * KTOT + c * 9 + k]);
  } else {
    int f2 = idx - KTOT * COUT;   // < 2304*32
    int t_ = f2 & 7;
    int rest = f2 >> 3;
    int j = rest & 31;
    int kk = (rest >> 5) * 8 + t_;
    int k = kk >> 8, c = kk & 255;
    float v = (j < 27) ? pw[j * KTOT + c * 9 + k] : 0.0f;
    PWs[f2] = f2bf(v);
  }
}

// ---------------- K1: NCHW -> NHWC transpose ----------------
__global__ __launch_bounds__(256) void transpose_x(const float* __restrict__ x,
                                                   float* __restrict__ xt) {
  __shared__ float tile[32][33];
  int b = blockIdx.z;
  int hw0 = blockIdx.x * 32;
  int c0 = blockIdx.y * 32;
  int tx = threadIdx.x, ty = threadIdx.y;
  for (int i = ty; i < 32; i += 8)
    tile[i][tx] = x[(size_t)(b * CIN + c0 + i) * HWS + hw0 + tx];
  __syncthreads();
  for (int r = ty; r < 32; r += 8)
    xt[(size_t)(b * HWS + hw0 + r) * CIN + c0 + tx] = tile[tx][r];
}

// ---------------- K2: offset conv, split-K, BM=64 ----------------
__global__ __launch_bounds__(256) void offset_conv_sk(const float* __restrict__ xt,
                                                      const unsigned short* __restrict__ PWs,
                                                      float* __restrict__ Pbuf) {
  __shared__ unsigned short Al[64 * 32];   // 4 KB
  __shared__ unsigned short Bl[1024];      // 2 KB
  int tid = threadIdx.x;
  int lane = tid & 63, wv = tid >> 6;
  int m0 = blockIdx.x * 64;
  int s = blockIdx.y;
  int b = m0 >> 12;
  int hw0 = m0 & 4095;
  f32x4 acc[2] = {};

  for (int tt = 0; tt < 72 / SPLITK; ++tt) {
    int t = s * (72 / SPLITK) + tt;
    int k = t >> 3, c0 = (t & 7) * 32;
    int dyk = k / 3 - 1;
    int dxk = k % 3 - 1;
    __syncthreads();
    *(uint2*)&Bl[tid * 4] = *(const uint2*)(PWs + (size_t)t * 1024 + tid * 4);
    {
      int r = tid >> 2;
      int q = (tid & 3) * 8;
      int hw = hw0 + r;
      int h = hw >> 6, wwp = hw & 63;
      int y = h + dyk, xx = wwp + dxk;
      float4 v0 = make_float4(0.f, 0.f, 0.f, 0.f);
      float4 v1 = make_float4(0.f, 0.f, 0.f, 0.f);
      if ((unsigned)y < 64u && (unsigned)xx < 64u) {
        const float* p = xt + ((size_t)((b << 12) + (y << 6) + xx) << 8) + c0 + q;
        v0 = *(const float4*)p;
        v1 = *(const float4*)(p + 4);
      }
      unsigned short u[8];
      u[0] = f2bf(v0.x); u[1] = f2bf(v0.y); u[2] = f2bf(v0.z); u[3] = f2bf(v0.w);
      u[4] = f2bf(v1.x); u[5] = f2bf(v1.y); u[6] = f2bf(v1.z); u[7] = f2bf(v1.w);
      *(uint4*)&Al[r * 32 + q] = *(const uint4*)u;
    }
    __syncthreads();
    int row = lane & 15, quad = lane >> 4;
    bf16x8 af = *(const bf16x8*)&Al[(wv * 16 + row) * 32 + quad * 8];
    for (int j = 0; j < 2; ++j) {
      bf16x8 bfr = *(const bf16x8*)&Bl[(quad * 32 + j * 16 + row) * 8];
      acc[j] = __builtin_amdgcn_mfma_f32_16x16x32_bf16(af, bfr, acc[j], 0, 0, 0);
    }
  }

  int row = lane & 15, quad = lane >> 4;
  for (int j = 0; j < 2; ++j) {
    int n = j * 16 + row;
    for (int r_ = 0; r_ < 4; ++r_) {
      int m = m0 + wv * 16 + quad * 4 + r_;
      Pbuf[((size_t)s * MTOT + m) * 32 + n] = acc[j][r_];
    }
  }
}

// ---------------- K2b: reduce split-K partials -> dy/dx/mask ----------------
__global__ __launch_bounds__(256) void reduce_offsets(const float* __restrict__ Pbuf,
                                                      const float* __restrict__ p_bias,
                                                      float* __restrict__ dyA,
                                                      float* __restrict__ dxA,
                                                      float* __restrict__ maskA) {
  int idx = blockIdx.x * 256 + threadIdx.x;  // m*32+n
  int n = idx & 31;
  int m = idx >> 5;
  float v = 0.f;
#pragma unroll
  for (int s = 0; s < SPLITK; ++s)
    v += Pbuf[(size_t)s * MTOT * 32 + idx];
  if (n < 27) {
    v += p_bias[n];
    if (n < 18) {
      if ((n & 1) == 0) dyA[m * 9 + (n >> 1)] = v;
      else              dxA[m * 9 + (n >> 1)] = v;
    } else {
      maskA[m * 9 + (n - 18)] = 1.0f / (1.0f + __expf(-v));
    }
  }
}

// ---------------- K3: bilinear sampling -> A bf16 ----------------
__global__ __launch_bounds__(256) void sample_kernel(const float* __restrict__ xt,
                                                     const float* __restrict__ dyA,
                                                     const float* __restrict__ dxA,
                                                     const float* __restrict__ maskA,
                                                     unsigned short* __restrict__ A) {
  int wv = threadIdx.x >> 6;
  int lane = threadIdx.x & 63;
  int task = blockIdx.x * 4 + wv;         // < 147456
  int m = task / 9;
  int k = task - m * 9;
  int b = m >> 12, hw = m & 4095, h = hw >> 6, ww = hw & 63;

  float dy = dyA[m * 9 + k];
  float dx = dxA[m * 9 + k];
  float mk = maskA[m * 9 + k];

  float py = (float)(h - 1 + k / 3) + dy;
  float px = (float)(ww - 1 + k % 3) + dx;
  float y0f = floorf(py), x0f = floorf(px);
  float ay = py - y0f, ax = px - x0f;
  int y0 = (int)y0f, x0 = (int)x0f;

  float w00 = (1.f - ay) * (1.f - ax) * mk;
  float w01 = (1.f - ay) * ax * mk;
  float w10 = ay * (1.f - ax) * mk;
  float w11 = ay * ax * mk;

  float vy0 = ((unsigned)y0 < 64u) ? 1.f : 0.f;
  float vy1 = ((unsigned)(y0 + 1) < 64u) ? 1.f : 0.f;
  float vx0 = ((unsigned)x0 < 64u) ? 1.f : 0.f;
  float vx1 = ((unsigned)(x0 + 1) < 64u) ? 1.f : 0.f;
  w00 *= vy0 * vx0; w01 *= vy0 * vx1; w10 *= vy1 * vx0; w11 *= vy1 * vx1;

  int yc0 = min(max(y0, 0), 63), yc1 = min(max(y0 + 1, 0), 63);
  int xc0 = min(max(x0, 0), 63), xc1 = min(max(x0 + 1, 0), 63);

  const float4* base = (const float4*)(xt + ((size_t)b << 12) * CIN);
  float4 t00 = base[(yc0 * 64 + xc0) * 64 + lane];
  float4 t01 = base[(yc0 * 64 + xc1) * 64 + lane];
  float4 t10 = base[(yc1 * 64 + xc0) * 64 + lane];
  float4 t11 = base[(yc1 * 64 + xc1) * 64 + lane];

  float4 r;
  r.x = w00 * t00.x + w01 * t01.x + w10 * t10.x + w11 * t11.x;
  r.y = w00 * t00.y + w01 * t01.y + w10 * t10.y + w11 * t11.y;
  r.z = w00 * t00.z + w01 * t01.z + w10 * t10.z + w11 * t11.z;
  r.w = w00 * t00.w + w01 * t01.w + w10 * t10.w + w11 * t11.w;

  ushort4 o;
  o.x = f2bf(r.x); o.y = f2bf(r.y); o.z = f2bf(r.z); o.w = f2bf(r.w);
  *(ushort4*)(A + (size_t)m * KTOT + k * 256 + lane * 4) = o;
}

// ---------------- K4: main GEMM 128x64, BK=64 (2x32), ping-pong dbuf ----------------
// One __syncthreads per iter; prefetch of t+1 issued before compute on t so
// the vmcnt(0) drain at the barrier is covered by the compute phase.
__global__ __launch_bounds__(256) void main_gemm(const unsigned short* __restrict__ Amat,
                                                 const unsigned short* __restrict__ WB,
                                                 const float* __restrict__ bias,
                                                 float* __restrict__ out) {
  // Al[buf][ks][128 rows x 32 kk] : 64B row stride (bank-safe, measured-fine)
  // Bl[buf][kb8(8) x col(64) x 8] : chunk-major (bank-clean)
  __shared__ unsigned short Al[2][2][128 * 32];  // 32 KB
  __shared__ unsigned short Bl[2][8 * 64 * 8];   // 16 KB
  int tid = threadIdx.x;
  int lane = tid & 63, wv = tid >> 6;
  int m0 = blockIdx.x * 128;
  int n0 = blockIdx.y * 64;
  int wm = wv * 32;
  f32x4 acc[2][4] = {};

  // stage tile t (BK=64) into buffer `buf`
  auto stage = [&](int t, int buf) {
    // A: 1024 chunks of 16B; thread -> 4 chunks
#pragma unroll
    for (int p = 0; p < 4; ++p) {
      int li = p * 256 + tid;
      int ks = li >> 9;          // 0..1 (wave-uniform: 512-aligned)
      int li2 = li & 511;
      int row = li2 >> 2, ch = li2 & 3;
      const unsigned short* src = Amat + (size_t)(m0 + row) * KTOT + t * 64 + ks * 32 + ch * 8;
      gload_lds16(src, &Al[buf][ks][li2 * 8]);
    }
    // B: 512 chunks of 16B; thread -> 2 chunks
#pragma unroll
    for (int p = 0; p < 2; ++p) {
      int li = p * 256 + tid;
      int kb8 = li >> 6, col = li & 63;
      const unsigned short* src = WB + ((size_t)(t * 8 + kb8) * 256 + n0 + col) * 8;
      gload_lds16(src, &Bl[buf][li * 8]);
    }
  };

  stage(0, 0);
  __syncthreads();   // drain: buf0 ready

  int row = lane & 15, quad = lane >> 4;
  for (int t = 0; t < 36; ++t) {
    int cur = t & 1;
    if (t < 35) stage(t + 1, cur ^ 1);   // async prefetch into idle buffer
#pragma unroll
    for (int ks = 0; ks < 2; ++ks) {
      bf16x8 af[2], bfr[4];
#pragma unroll
      for (int i = 0; i < 2; ++i)
        af[i] = *(const bf16x8*)&Al[cur][ks][(wm + i * 16 + row) * 32 + quad * 8];
#pragma unroll
      for (int j = 0; j < 4; ++j)
        bfr[j] = *(const bf16x8*)&Bl[cur][((ks * 4 + quad) * 64 + j * 16 + row) * 8];
#pragma unroll
      for (int i = 0; i < 2; ++i)
#pragma unroll
        for (int j = 0; j < 4; ++j)
          acc[i][j] = __builtin_amdgcn_mfma_f32_16x16x32_bf16(af[i], bfr[j], acc[i][j], 0, 0, 0);
    }
    __syncthreads();  // waits prefetch (vmcnt) + all waves done reading cur
  }

  int b = m0 >> 12, hw0 = m0 & 4095;
  for (int j = 0; j < 4; ++j) {
    int o = n0 + j * 16 + row;
    float bo = bias[o];
    for (int i = 0; i < 2; ++i) {
      int hw = hw0 + wm + i * 16 + quad * 4;
      float4 v;
      v.x = acc[i][j][0] + bo;
      v.y = acc[i][j][1] + bo;
      v.z = acc[i][j][2] + bo;
      v.w = acc[i][j][3] + bo;
      *(float4*)(out + (((size_t)(b * COUT + o)) << 12) + hw) = v;
    }
  }
}

// ---------------- launch ----------------
extern "C" void kernel_launch(void* const* d_in, const int* in_sizes, int n_in,
                              void* d_out, int out_size, void* d_ws, size_t ws_size,
                              hipStream_t stream) {
  const float* x        = (const float*)d_in[0];
  const float* weight   = (const float*)d_in[1];
  const float* bias     = (const float*)d_in[2];
  const float* p_weight = (const float*)d_in[3];
  const float* p_bias   = (const float*)d_in[4];
  float* out = (float*)d_out;
  char* ws = (char*)d_ws;

  const size_t OFF_XT   = 0;                          // 16,777,216  fp32 NHWC x
  const size_t OFF_DY   = 16777216;                   //    589,824
  const size_t OFF_DX   = OFF_DY + 589824;            //    589,824
  const size_t OFF_MASK = OFF_DX + 589824;            //    589,824
  const size_t OFF_WB   = OFF_MASK + 589824;          //  1,179,648  bf16
  const size_t OFF_PW   = OFF_WB + 1179648;           //    147,456  bf16
  const size_t OFF_A    = OFF_PW + 147456;            // 75,497,472  bf16

  float* xt   = (float*)(ws + OFF_XT);
  float* dyA  = (float*)(ws + OFF_DY);
  float* dxA  = (float*)(ws + OFF_DX);
  float* mskA = (float*)(ws + OFF_MASK);
  unsigned short* WB   = (unsigned short*)(ws + OFF_WB);
  unsigned short* PWs  = (unsigned short*)(ws + OFF_PW);
  unsigned short* Amat = (unsigned short*)(ws + OFF_A);
  float* Pbuf = (float*)(ws + OFF_A);

  prep_weights<<<(KTOT * COUT + KTOT * 32) / 256, 256, 0, stream>>>(weight, p_weight, WB, PWs);
  transpose_x<<<dim3(128, 8, 4), dim3(32, 8), 0, stream>>>(x, xt);
  offset_conv_sk<<<dim3(MTOT / 64, SPLITK), 256, 0, stream>>>(xt, PWs, Pbuf);
  reduce_offsets<<<(MTOT * 32) / 256, 256, 0, stream>>>(Pbuf, p_bias, dyA, dxA, mskA);
  sample_kernel<<<(MTOT * 9) / 4, 256, 0, stream>>>(xt, dyA, dxA, mskA, Amat);
  main_gemm<<<dim3(MTOT / 128, COUT / 64), 256, 0, stream>>>(Amat, WB, bias, out);
}